// Round 6
// baseline (310.261 us; speedup 1.0000x reference)
//
#include <hip/hip_runtime.h>

#define VOCAB 32000
#define DIM 2048
#define N_LORA 9
#define RANK 16
#define NSEG 16
#define TB 32          // tokens per block tile in main kernel
#define BLOCK 256      // each thread owns 2 dims -> 512 dims/block -> grid.y = 4

typedef float f32x4 __attribute__((ext_vector_type(4)));
typedef float f32x2 __attribute__((ext_vector_type(2)));

// ---------------- K1: per-token prep ----------------
// One thread per (token, quad). seg -> lora slot -> scale, gather + pre-scale
// A row. Scratch: float a_sc[T][16] then int w_arr[T].
__global__ void prep_kernel(
    const int* __restrict__ input_ids,
    const float* __restrict__ A_buffer,
    const int* __restrict__ seg_indptr,
    const int* __restrict__ weight_indices,
    const float* __restrict__ scalings,
    float* __restrict__ a_sc,
    int* __restrict__ w_arr,
    int T)
{
    const int g = blockIdx.x * blockDim.x + threadIdx.x;
    const int t = g >> 2, q = g & 3;
    if (t >= T) return;

    const int id = input_ids[t];
    int seg = -1;
    #pragma unroll
    for (int i = 0; i < NSEG; ++i)
        seg += (seg_indptr[i] <= t) ? 1 : 0;
    const int w = weight_indices[seg];
    const float s = (w != 0) ? scalings[w] : 0.0f;
    if (q == 0) w_arr[t] = w;

    const f32x4* arow = reinterpret_cast<const f32x4*>(
        A_buffer + ((size_t)w * VOCAB + (size_t)id) * RANK);
    f32x4 av = arow[q] * s;
    *reinterpret_cast<f32x4*>(a_sc + (size_t)t * RANK + q * 4) = av;
}

// ---------------- K2: main streaming kernel ----------------
// 2 dims/thread keeps the register-resident B cache at 8 f32x4 (32 VGPR) so
// total VGPR stays under the 128 occupancy step -> 4 blocks/CU (16 waves/CU).
__device__ __forceinline__ void token_body(
    int tk, int t0, int d,
    const int* __restrict__ ids_s,
    const int* __restrict__ w_s,
    const f32x4 (* __restrict__ a_s)[RANK / 4],
    const float* __restrict__ weight,
    const float* __restrict__ B_buffer,
    float* __restrict__ out,
    f32x4 (&b)[8], int& wcur)
{
    const int w = w_s[tk];                    // wave-uniform LDS broadcast
    if (w != wcur) {                          // uniform branch, rare
        wcur = w;
        // B rows for dims d, d+1: 32 consecutive floats = 8 f32x4
        const f32x4* bp = reinterpret_cast<const f32x4*>(
            B_buffer + ((size_t)w * DIM + (size_t)d) * RANK);
        #pragma unroll
        for (int j = 0; j < 8; ++j) b[j] = bp[j];
    }
    const f32x4 a0 = a_s[tk][0], a1 = a_s[tk][1], a2 = a_s[tk][2], a3 = a_s[tk][3];
    const f32x2 wv = *reinterpret_cast<const f32x2*>(
        weight + (size_t)ids_s[tk] * DIM + d);
    f32x2 o;
    o.x = wv.x
        + b[0].x*a0.x + b[0].y*a0.y + b[0].z*a0.z + b[0].w*a0.w
        + b[1].x*a1.x + b[1].y*a1.y + b[1].z*a1.z + b[1].w*a1.w
        + b[2].x*a2.x + b[2].y*a2.y + b[2].z*a2.z + b[2].w*a2.w
        + b[3].x*a3.x + b[3].y*a3.y + b[3].z*a3.z + b[3].w*a3.w;
    o.y = wv.y
        + b[4].x*a0.x + b[4].y*a0.y + b[4].z*a0.z + b[4].w*a0.w
        + b[5].x*a1.x + b[5].y*a1.y + b[5].z*a1.z + b[5].w*a1.w
        + b[6].x*a2.x + b[6].y*a2.y + b[6].z*a2.z + b[6].w*a2.w
        + b[7].x*a3.x + b[7].y*a3.y + b[7].z*a3.z + b[7].w*a3.w;
    *reinterpret_cast<f32x2*>(out + (size_t)(t0 + tk) * DIM + d) = o;
}

__global__ __launch_bounds__(BLOCK, 4) void lora_embed_kernel(
    const int* __restrict__ input_ids,
    const float* __restrict__ weight,
    const float* __restrict__ B_buffer,
    const float* __restrict__ a_sc,
    const int* __restrict__ w_arr,
    float* __restrict__ out,
    int T)
{
    __shared__ int ids_s[TB];
    __shared__ int w_s[TB];
    __shared__ f32x4 a_s[TB][RANK / 4];

    const int tid = threadIdx.x;
    const int t0 = blockIdx.x * TB;

    // Cheap preamble: independent coalesced loads, one barrier.
    if (tid < TB) {
        int tg = t0 + tid;
        int tc = tg < T ? tg : T - 1;
        ids_s[tid] = input_ids[tc];
        w_s[tid] = w_arr[tc];
    }
    {   // TB*RANK == 512 floats; 2 per thread, coalesced
        float* as = reinterpret_cast<float*>(a_s);
        const size_t base = (size_t)t0 * RANK;
        const size_t cap = (size_t)T * RANK - 1;
        size_t i0 = base + tid, i1 = base + BLOCK + tid;
        as[tid]         = a_sc[i0 < cap ? i0 : cap];
        as[BLOCK + tid] = a_sc[i1 < cap ? i1 : cap];
    }
    __syncthreads();

    const int d = (blockIdx.y * BLOCK + tid) * 2;

    f32x4 b[8];
    int wcur = -1;

    if (t0 + TB <= T) {
        #pragma unroll 8
        for (int tk = 0; tk < TB; ++tk)
            token_body(tk, t0, d, ids_s, w_s, a_s, weight, B_buffer, out, b, wcur);
    } else {
        const int nt = T - t0;
        for (int tk = 0; tk < nt; ++tk)
            token_body(tk, t0, d, ids_s, w_s, a_s, weight, B_buffer, out, b, wcur);
    }
}

extern "C" void kernel_launch(void* const* d_in, const int* in_sizes, int n_in,
                              void* d_out, int out_size, void* d_ws, size_t ws_size,
                              hipStream_t stream) {
    const int*   input_ids      = (const int*)d_in[0];
    const float* weight         = (const float*)d_in[1];
    const float* A_buffer       = (const float*)d_in[2];
    const float* B_buffer       = (const float*)d_in[3];
    const int*   seg_indptr     = (const int*)d_in[4];
    const int*   weight_indices = (const int*)d_in[5];
    const float* scalings       = (const float*)d_in[6];
    float* out = (float*)d_out;

    const int T = in_sizes[0];

    // scratch layout: a_sc[T][RANK] floats, then w_arr[T] ints (~544 KB)
    float* a_sc  = (float*)d_ws;
    int*   w_arr = (int*)((char*)d_ws + (size_t)T * RANK * sizeof(float));

    prep_kernel<<<(T * 4 + BLOCK - 1) / BLOCK, BLOCK, 0, stream>>>(
        input_ids, A_buffer, seg_indptr, weight_indices, scalings,
        a_sc, w_arr, T);

    dim3 grid((T + TB - 1) / TB, DIM / (BLOCK * 2));
    lora_embed_kernel<<<grid, BLOCK, 0, stream>>>(
        input_ids, weight, B_buffer, a_sc, w_arr, out, T);
}

// Round 7
// 54.961 us; speedup vs baseline: 5.6451x; 5.6451x over previous
//
#include <hip/hip_runtime.h>

#define VOCAB 32000
#define DIM 2048
#define N_LORA 9
#define RANK 16
#define NSEG 16
#define TB 32          // tokens per block tile in main kernel
#define BLOCK 256      // each thread owns 2 dims -> 512 dims/block -> grid.y = 4

typedef float f32x4 __attribute__((ext_vector_type(4)));
typedef float f32x2 __attribute__((ext_vector_type(2)));

// ---------------- K1: per-token prep ----------------
// One thread per (token, quad). seg -> lora slot -> scale, gather + pre-scale
// A row. Scratch: float a_sc[T][16] then int w_arr[T].
__global__ void prep_kernel(
    const int* __restrict__ input_ids,
    const float* __restrict__ A_buffer,
    const int* __restrict__ seg_indptr,
    const int* __restrict__ weight_indices,
    const float* __restrict__ scalings,
    float* __restrict__ a_sc,
    int* __restrict__ w_arr,
    int T)
{
    const int g = blockIdx.x * blockDim.x + threadIdx.x;
    const int t = g >> 2, q = g & 3;
    if (t >= T) return;

    const int id = input_ids[t];
    int seg = -1;
    #pragma unroll
    for (int i = 0; i < NSEG; ++i)
        seg += (seg_indptr[i] <= t) ? 1 : 0;
    const int w = weight_indices[seg];
    const float s = (w != 0) ? scalings[w] : 0.0f;
    if (q == 0) w_arr[t] = w;

    const f32x4* arow = reinterpret_cast<const f32x4*>(
        A_buffer + ((size_t)w * VOCAB + (size_t)id) * RANK);
    f32x4 av = arow[q] * s;
    *reinterpret_cast<f32x4*>(a_sc + (size_t)t * RANK + q * 4) = av;
}

// ---------------- K2: main streaming kernel ----------------
// 2 dims/thread keeps the register-resident B cache at 8 f32x4 (32 VGPR).
// NO waves-per-EU hint: R6 showed __launch_bounds__(256,4) shrank the budget
// to 64 VGPR and spilled ~1 GB of scratch. Let the allocator pick (~100-120
// VGPR -> <=128 bucket -> 4 waves/EU naturally).
__device__ __forceinline__ void token_body(
    int tk, int t0, int d,
    const int* __restrict__ ids_s,
    const int* __restrict__ w_s,
    const f32x4 (* __restrict__ a_s)[RANK / 4],
    const float* __restrict__ weight,
    const float* __restrict__ B_buffer,
    float* __restrict__ out,
    f32x4 (&b)[8], int& wcur)
{
    const int w = w_s[tk];                    // wave-uniform LDS broadcast
    if (w != wcur) {                          // uniform branch, rare
        wcur = w;
        // B rows for dims d, d+1: 32 consecutive floats = 8 f32x4
        const f32x4* bp = reinterpret_cast<const f32x4*>(
            B_buffer + ((size_t)w * DIM + (size_t)d) * RANK);
        #pragma unroll
        for (int j = 0; j < 8; ++j) b[j] = bp[j];
    }
    const f32x4 a0 = a_s[tk][0], a1 = a_s[tk][1], a2 = a_s[tk][2], a3 = a_s[tk][3];
    const f32x2 wv = *reinterpret_cast<const f32x2*>(
        weight + (size_t)ids_s[tk] * DIM + d);
    f32x2 o;
    o.x = wv.x
        + b[0].x*a0.x + b[0].y*a0.y + b[0].z*a0.z + b[0].w*a0.w
        + b[1].x*a1.x + b[1].y*a1.y + b[1].z*a1.z + b[1].w*a1.w
        + b[2].x*a2.x + b[2].y*a2.y + b[2].z*a2.z + b[2].w*a2.w
        + b[3].x*a3.x + b[3].y*a3.y + b[3].z*a3.z + b[3].w*a3.w;
    o.y = wv.y
        + b[4].x*a0.x + b[4].y*a0.y + b[4].z*a0.z + b[4].w*a0.w
        + b[5].x*a1.x + b[5].y*a1.y + b[5].z*a1.z + b[5].w*a1.w
        + b[6].x*a2.x + b[6].y*a2.y + b[6].z*a2.z + b[6].w*a2.w
        + b[7].x*a3.x + b[7].y*a3.y + b[7].z*a3.z + b[7].w*a3.w;
    *reinterpret_cast<f32x2*>(out + (size_t)(t0 + tk) * DIM + d) = o;
}

__global__ __launch_bounds__(BLOCK) void lora_embed_kernel(
    const int* __restrict__ input_ids,
    const float* __restrict__ weight,
    const float* __restrict__ B_buffer,
    const float* __restrict__ a_sc,
    const int* __restrict__ w_arr,
    float* __restrict__ out,
    int T)
{
    __shared__ int ids_s[TB];
    __shared__ int w_s[TB];
    __shared__ f32x4 a_s[TB][RANK / 4];

    const int tid = threadIdx.x;
    const int t0 = blockIdx.x * TB;

    // Cheap preamble: independent coalesced loads, one barrier.
    if (tid < TB) {
        int tg = t0 + tid;
        int tc = tg < T ? tg : T - 1;
        ids_s[tid] = input_ids[tc];
        w_s[tid] = w_arr[tc];
    }
    {   // TB*RANK == 512 floats; 2 per thread, coalesced
        float* as = reinterpret_cast<float*>(a_s);
        const size_t base = (size_t)t0 * RANK;
        const size_t cap = (size_t)T * RANK - 1;
        size_t i0 = base + tid, i1 = base + BLOCK + tid;
        as[tid]         = a_sc[i0 < cap ? i0 : cap];
        as[BLOCK + tid] = a_sc[i1 < cap ? i1 : cap];
    }
    __syncthreads();

    const int d = (blockIdx.y * BLOCK + tid) * 2;

    f32x4 b[8];
    int wcur = -1;

    if (t0 + TB <= T) {
        #pragma unroll 4
        for (int tk = 0; tk < TB; ++tk)
            token_body(tk, t0, d, ids_s, w_s, a_s, weight, B_buffer, out, b, wcur);
    } else {
        const int nt = T - t0;
        for (int tk = 0; tk < nt; ++tk)
            token_body(tk, t0, d, ids_s, w_s, a_s, weight, B_buffer, out, b, wcur);
    }
}

extern "C" void kernel_launch(void* const* d_in, const int* in_sizes, int n_in,
                              void* d_out, int out_size, void* d_ws, size_t ws_size,
                              hipStream_t stream) {
    const int*   input_ids      = (const int*)d_in[0];
    const float* weight         = (const float*)d_in[1];
    const float* A_buffer       = (const float*)d_in[2];
    const float* B_buffer       = (const float*)d_in[3];
    const int*   seg_indptr     = (const int*)d_in[4];
    const int*   weight_indices = (const int*)d_in[5];
    const float* scalings       = (const float*)d_in[6];
    float* out = (float*)d_out;

    const int T = in_sizes[0];

    // scratch layout: a_sc[T][RANK] floats, then w_arr[T] ints (~544 KB)
    float* a_sc  = (float*)d_ws;
    int*   w_arr = (int*)((char*)d_ws + (size_t)T * RANK * sizeof(float));

    prep_kernel<<<(T * 4 + BLOCK - 1) / BLOCK, BLOCK, 0, stream>>>(
        input_ids, A_buffer, seg_indptr, weight_indices, scalings,
        a_sc, w_arr, T);

    dim3 grid((T + TB - 1) / TB, DIM / (BLOCK * 2));
    lora_embed_kernel<<<grid, BLOCK, 0, stream>>>(
        input_ids, weight, B_buffer, a_sc, w_arr, out, T);
}

// Round 8
// 39.948 us; speedup vs baseline: 7.7666x; 1.3758x over previous
//
#include <hip/hip_runtime.h>

#define VOCAB 32000
#define DIM 2048
#define N_LORA 9
#define RANK 16
#define NSEG 16
#define TB 16          // tokens per block tile (cheap preamble now; 2x blocks of R1)
#define BLOCK 256      // each thread owns 4 consecutive dims -> 1024 dims/block

typedef float f32x4 __attribute__((ext_vector_type(4)));

// ---------------- K1: per-token prep ----------------
// One thread per (token, quad). seg -> lora slot -> scale, gather + pre-scale
// A row. Scratch: float a_sc[T][16] then int w_arr[T].
__global__ void prep_kernel(
    const int* __restrict__ input_ids,
    const float* __restrict__ A_buffer,
    const int* __restrict__ seg_indptr,
    const int* __restrict__ weight_indices,
    const float* __restrict__ scalings,
    float* __restrict__ a_sc,
    int* __restrict__ w_arr,
    int T)
{
    const int g = blockIdx.x * blockDim.x + threadIdx.x;
    const int t = g >> 2, q = g & 3;
    if (t >= T) return;

    const int id = input_ids[t];
    int seg = -1;
    #pragma unroll
    for (int i = 0; i < NSEG; ++i)
        seg += (seg_indptr[i] <= t) ? 1 : 0;
    const int w = weight_indices[seg];
    const float s = (w != 0) ? scalings[w] : 0.0f;
    if (q == 0) w_arr[t] = w;

    const f32x4* arow = reinterpret_cast<const f32x4*>(
        A_buffer + ((size_t)w * VOCAB + (size_t)id) * RANK);
    f32x4 av = arow[q] * s;
    *reinterpret_cast<f32x4*>(a_sc + (size_t)t * RANK + q * 4) = av;
}

// ---------------- K2: main streaming kernel (R1 structure, TB=16) ----------
__device__ __forceinline__ void token_body(
    int tk, int t0, int d,
    const int* __restrict__ ids_s,
    const int* __restrict__ w_s,
    const f32x4 (* __restrict__ a_s)[RANK / 4],
    const float* __restrict__ weight,
    const float* __restrict__ B_buffer,
    float* __restrict__ out,
    f32x4 (&b)[16], int& wcur)
{
    const int w = w_s[tk];                    // wave-uniform LDS broadcast
    if (w != wcur) {                          // uniform branch, rare
        wcur = w;
        const f32x4* bp = reinterpret_cast<const f32x4*>(
            B_buffer + ((size_t)w * DIM + (size_t)d) * RANK);
        #pragma unroll
        for (int j = 0; j < 16; ++j) b[j] = bp[j];
    }
    const f32x4 a0 = a_s[tk][0], a1 = a_s[tk][1], a2 = a_s[tk][2], a3 = a_s[tk][3];
    const f32x4 wv = *reinterpret_cast<const f32x4*>(
        weight + (size_t)ids_s[tk] * DIM + d);
    f32x4 o;
    o.x = wv.x
        + b[ 0].x*a0.x + b[ 0].y*a0.y + b[ 0].z*a0.z + b[ 0].w*a0.w
        + b[ 1].x*a1.x + b[ 1].y*a1.y + b[ 1].z*a1.z + b[ 1].w*a1.w
        + b[ 2].x*a2.x + b[ 2].y*a2.y + b[ 2].z*a2.z + b[ 2].w*a2.w
        + b[ 3].x*a3.x + b[ 3].y*a3.y + b[ 3].z*a3.z + b[ 3].w*a3.w;
    o.y = wv.y
        + b[ 4].x*a0.x + b[ 4].y*a0.y + b[ 4].z*a0.z + b[ 4].w*a0.w
        + b[ 5].x*a1.x + b[ 5].y*a1.y + b[ 5].z*a1.z + b[ 5].w*a1.w
        + b[ 6].x*a2.x + b[ 6].y*a2.y + b[ 6].z*a2.z + b[ 6].w*a2.w
        + b[ 7].x*a3.x + b[ 7].y*a3.y + b[ 7].z*a3.z + b[ 7].w*a3.w;
    o.z = wv.z
        + b[ 8].x*a0.x + b[ 8].y*a0.y + b[ 8].z*a0.z + b[ 8].w*a0.w
        + b[ 9].x*a1.x + b[ 9].y*a1.y + b[ 9].z*a1.z + b[ 9].w*a1.w
        + b[10].x*a2.x + b[10].y*a2.y + b[10].z*a2.z + b[10].w*a2.w
        + b[11].x*a3.x + b[11].y*a3.y + b[11].z*a3.z + b[11].w*a3.w;
    o.w = wv.w
        + b[12].x*a0.x + b[12].y*a0.y + b[12].z*a0.z + b[12].w*a0.w
        + b[13].x*a1.x + b[13].y*a1.y + b[13].z*a1.z + b[13].w*a1.w
        + b[14].x*a2.x + b[14].y*a2.y + b[14].z*a2.z + b[14].w*a2.w
        + b[15].x*a3.x + b[15].y*a3.y + b[15].z*a3.z + b[15].w*a3.w;
    *reinterpret_cast<f32x4*>(out + (size_t)(t0 + tk) * DIM + d) = o;
}

__global__ __launch_bounds__(BLOCK) void lora_embed_kernel(
    const int* __restrict__ input_ids,
    const float* __restrict__ weight,
    const float* __restrict__ B_buffer,
    const float* __restrict__ a_sc,
    const int* __restrict__ w_arr,
    float* __restrict__ out,
    int T)
{
    __shared__ int ids_s[TB];
    __shared__ int w_s[TB];
    __shared__ f32x4 a_s[TB][RANK / 4];

    const int tid = threadIdx.x;
    const int t0 = blockIdx.x * TB;

    // Cheap preamble: independent coalesced loads, one barrier.
    if (tid < TB) {
        int tg = t0 + tid;
        int tc = tg < T ? tg : T - 1;
        ids_s[tid] = input_ids[tc];
        w_s[tid] = w_arr[tc];
    }
    {   // TB*RANK == 256 floats == one per thread, coalesced
        size_t idx = (size_t)t0 * RANK + tid;
        size_t cap = (size_t)T * RANK - 1;
        reinterpret_cast<float*>(a_s)[tid] = a_sc[idx < cap ? idx : cap];
    }
    __syncthreads();

    const int d = (blockIdx.y * BLOCK + tid) * 4;

    f32x4 b[16];
    int wcur = -1;

    if (t0 + TB <= T) {
        #pragma unroll 4
        for (int tk = 0; tk < TB; ++tk)
            token_body(tk, t0, d, ids_s, w_s, a_s, weight, B_buffer, out, b, wcur);
    } else {
        const int nt = T - t0;
        for (int tk = 0; tk < nt; ++tk)
            token_body(tk, t0, d, ids_s, w_s, a_s, weight, B_buffer, out, b, wcur);
    }
}

extern "C" void kernel_launch(void* const* d_in, const int* in_sizes, int n_in,
                              void* d_out, int out_size, void* d_ws, size_t ws_size,
                              hipStream_t stream) {
    const int*   input_ids      = (const int*)d_in[0];
    const float* weight         = (const float*)d_in[1];
    const float* A_buffer       = (const float*)d_in[2];
    const float* B_buffer       = (const float*)d_in[3];
    const int*   seg_indptr     = (const int*)d_in[4];
    const int*   weight_indices = (const int*)d_in[5];
    const float* scalings       = (const float*)d_in[6];
    float* out = (float*)d_out;

    const int T = in_sizes[0];

    // scratch layout: a_sc[T][RANK] floats, then w_arr[T] ints (~544 KB)
    float* a_sc  = (float*)d_ws;
    int*   w_arr = (int*)((char*)d_ws + (size_t)T * RANK * sizeof(float));

    prep_kernel<<<(T * 4 + BLOCK - 1) / BLOCK, BLOCK, 0, stream>>>(
        input_ids, A_buffer, seg_indptr, weight_indices, scalings,
        a_sc, w_arr, T);

    dim3 grid((T + TB - 1) / TB, DIM / (BLOCK * 4));
    lora_embed_kernel<<<grid, BLOCK, 0, stream>>>(
        input_ids, weight, B_buffer, a_sc, w_arr, out, T);
}

// Round 9
// 37.950 us; speedup vs baseline: 8.1756x; 1.0527x over previous
//
#include <hip/hip_runtime.h>

#define VOCAB 32000
#define DIM 2048
#define N_LORA 9
#define RANK 16
#define NSEG 16
#define TB 32          // tokens per block tile
#define BLOCK 512      // 8 waves; each thread owns 4 dims -> block covers ALL 2048 dims

typedef float f32x4 __attribute__((ext_vector_type(4)));

// ---------------- K1: per-token prep ----------------
// One thread per (token, quad). seg -> lora slot -> scale, gather + pre-scale
// A row. Scratch: float a_sc[T][16] then int w_arr[T].
__global__ void prep_kernel(
    const int* __restrict__ input_ids,
    const float* __restrict__ A_buffer,
    const int* __restrict__ seg_indptr,
    const int* __restrict__ weight_indices,
    const float* __restrict__ scalings,
    float* __restrict__ a_sc,
    int* __restrict__ w_arr,
    int T)
{
    const int g = blockIdx.x * blockDim.x + threadIdx.x;
    const int t = g >> 2, q = g & 3;
    if (t >= T) return;

    const int id = input_ids[t];
    int seg = -1;
    #pragma unroll
    for (int i = 0; i < NSEG; ++i)
        seg += (seg_indptr[i] <= t) ? 1 : 0;
    const int w = weight_indices[seg];
    const float s = (w != 0) ? scalings[w] : 0.0f;
    if (q == 0) w_arr[t] = w;

    const f32x4* arow = reinterpret_cast<const f32x4*>(
        A_buffer + ((size_t)w * VOCAB + (size_t)id) * RANK);
    f32x4 av = arow[q] * s;
    *reinterpret_cast<f32x4*>(a_sc + (size_t)t * RANK + q * 4) = av;
}

// ---------------- K2: main streaming kernel ----------------
// One block = 512 threads = all 2048 dims of a token. Each token's 8 KB
// weight row is fetched as ONE contiguous burst (8 waves x 1 KB issued
// together) instead of two uncorrelated 4 KB slices (R1's grid.y=2).
// DRAM row-buffer locality is the lever under test this round.
__device__ __forceinline__ void token_body(
    int tk, int t0, int d,
    const int* __restrict__ ids_s,
    const int* __restrict__ w_s,
    const f32x4 (* __restrict__ a_s)[RANK / 4],
    const float* __restrict__ weight,
    const float* __restrict__ B_buffer,
    float* __restrict__ out,
    f32x4 (&b)[16], int& wcur)
{
    const int w = w_s[tk];                    // wave-uniform LDS broadcast
    if (w != wcur) {                          // uniform branch, rare
        wcur = w;
        const f32x4* bp = reinterpret_cast<const f32x4*>(
            B_buffer + ((size_t)w * DIM + (size_t)d) * RANK);
        #pragma unroll
        for (int j = 0; j < 16; ++j) b[j] = bp[j];
    }
    const f32x4 a0 = a_s[tk][0], a1 = a_s[tk][1], a2 = a_s[tk][2], a3 = a_s[tk][3];
    const f32x4 wv = *reinterpret_cast<const f32x4*>(
        weight + (size_t)ids_s[tk] * DIM + d);
    f32x4 o;
    o.x = wv.x
        + b[ 0].x*a0.x + b[ 0].y*a0.y + b[ 0].z*a0.z + b[ 0].w*a0.w
        + b[ 1].x*a1.x + b[ 1].y*a1.y + b[ 1].z*a1.z + b[ 1].w*a1.w
        + b[ 2].x*a2.x + b[ 2].y*a2.y + b[ 2].z*a2.z + b[ 2].w*a2.w
        + b[ 3].x*a3.x + b[ 3].y*a3.y + b[ 3].z*a3.z + b[ 3].w*a3.w;
    o.y = wv.y
        + b[ 4].x*a0.x + b[ 4].y*a0.y + b[ 4].z*a0.z + b[ 4].w*a0.w
        + b[ 5].x*a1.x + b[ 5].y*a1.y + b[ 5].z*a1.z + b[ 5].w*a1.w
        + b[ 6].x*a2.x + b[ 6].y*a2.y + b[ 6].z*a2.z + b[ 6].w*a2.w
        + b[ 7].x*a3.x + b[ 7].y*a3.y + b[ 7].z*a3.z + b[ 7].w*a3.w;
    o.z = wv.z
        + b[ 8].x*a0.x + b[ 8].y*a0.y + b[ 8].z*a0.z + b[ 8].w*a0.w
        + b[ 9].x*a1.x + b[ 9].y*a1.y + b[ 9].z*a1.z + b[ 9].w*a1.w
        + b[10].x*a2.x + b[10].y*a2.y + b[10].z*a2.z + b[10].w*a2.w
        + b[11].x*a3.x + b[11].y*a3.y + b[11].z*a3.z + b[11].w*a3.w;
    o.w = wv.w
        + b[12].x*a0.x + b[12].y*a0.y + b[12].z*a0.z + b[12].w*a0.w
        + b[13].x*a1.x + b[13].y*a1.y + b[13].z*a1.z + b[13].w*a1.w
        + b[14].x*a2.x + b[14].y*a2.y + b[14].z*a2.z + b[14].w*a2.w
        + b[15].x*a3.x + b[15].y*a3.y + b[15].z*a3.z + b[15].w*a3.w;
    *reinterpret_cast<f32x4*>(out + (size_t)(t0 + tk) * DIM + d) = o;
}

__global__ __launch_bounds__(BLOCK) void lora_embed_kernel(
    const int* __restrict__ input_ids,
    const float* __restrict__ weight,
    const float* __restrict__ B_buffer,
    const float* __restrict__ a_sc,
    const int* __restrict__ w_arr,
    float* __restrict__ out,
    int T)
{
    __shared__ int ids_s[TB];
    __shared__ int w_s[TB];
    __shared__ f32x4 a_s[TB][RANK / 4];

    const int tid = threadIdx.x;
    const int t0 = blockIdx.x * TB;

    // Cheap preamble: independent coalesced loads, one barrier.
    if (tid < TB) {
        int tg = t0 + tid;
        int tc = tg < T ? tg : T - 1;
        ids_s[tid] = input_ids[tc];
        w_s[tid] = w_arr[tc];
    }
    {   // TB*RANK == 512 floats == one per thread, coalesced
        size_t idx = (size_t)t0 * RANK + tid;
        size_t cap = (size_t)T * RANK - 1;
        reinterpret_cast<float*>(a_s)[tid] = a_sc[idx < cap ? idx : cap];
    }
    __syncthreads();

    const int d = tid * 4;   // all 2048 dims covered by one block

    f32x4 b[16];
    int wcur = -1;

    if (t0 + TB <= T) {
        #pragma unroll 4
        for (int tk = 0; tk < TB; ++tk)
            token_body(tk, t0, d, ids_s, w_s, a_s, weight, B_buffer, out, b, wcur);
    } else {
        const int nt = T - t0;
        for (int tk = 0; tk < nt; ++tk)
            token_body(tk, t0, d, ids_s, w_s, a_s, weight, B_buffer, out, b, wcur);
    }
}

extern "C" void kernel_launch(void* const* d_in, const int* in_sizes, int n_in,
                              void* d_out, int out_size, void* d_ws, size_t ws_size,
                              hipStream_t stream) {
    const int*   input_ids      = (const int*)d_in[0];
    const float* weight         = (const float*)d_in[1];
    const float* A_buffer       = (const float*)d_in[2];
    const float* B_buffer       = (const float*)d_in[3];
    const int*   seg_indptr     = (const int*)d_in[4];
    const int*   weight_indices = (const int*)d_in[5];
    const float* scalings       = (const float*)d_in[6];
    float* out = (float*)d_out;

    const int T = in_sizes[0];

    // scratch layout: a_sc[T][RANK] floats, then w_arr[T] ints (~544 KB)
    float* a_sc  = (float*)d_ws;
    int*   w_arr = (int*)((char*)d_ws + (size_t)T * RANK * sizeof(float));

    prep_kernel<<<(T * 4 + 255) / 256, 256, 0, stream>>>(
        input_ids, A_buffer, seg_indptr, weight_indices, scalings,
        a_sc, w_arr, T);

    dim3 grid((T + TB - 1) / TB);
    lora_embed_kernel<<<grid, BLOCK, 0, stream>>>(
        input_ids, weight, B_buffer, a_sc, w_arr, out, T);
}